// Round 15
// baseline (224.843 us; speedup 1.0000x reference)
//
#include <hip/hip_runtime.h>
#include <hip/hip_bf16.h>
#include <math.h>

#define NFEAT 128
#define NHID 64
#define NCLASS 47
#define NLAYERS 4
#define CAP 80       // max in-degree slots; deg ~ Poisson(25), P(>80) ~ 1e-17/node
#define NBUCK 128
#define BSHIFT 9     // bucket = c >> 9 (512 nodes per bucket)
#define BSLICE 512
#define BCAP 16384   // entries per bucket (mean 12.8K, +31 sigma headroom)
#define BK_EPB 2048
#define AFW 72       // fp16 LDS row stride (elements): 144 B
#define XEW 136      // encoder fp16 LDS row stride: 272 B

typedef __attribute__((ext_vector_type(8))) _Float16 half8;
typedef __attribute__((ext_vector_type(4))) float f32x4;

// -------- init: gcur + fp16 MFMA B-fragments for Enc, W, W2, Dec + bc/te ----
// B-frag layout for mfma_f32_16x16x32_f16: lane l holds B[k][n], n = l&15,
// k = kt*32 + (l>>4)*8 + i (i=0..7). A uses the same slot->k bijection.

__global__ __launch_bounds__(256) void k_init(int* __restrict__ gcur,
                                              const float* __restrict__ enc_w,
                                              const float* __restrict__ conv_w,
                                              const float* __restrict__ res_w,
                                              const float* __restrict__ conv_b,
                                              const float* __restrict__ res_b,
                                              const float* __restrict__ eps,
                                              const float* __restrict__ dec_w,
                                              _Float16* __restrict__ Enchb,
                                              _Float16* __restrict__ Whb,
                                              _Float16* __restrict__ W2hb,
                                              _Float16* __restrict__ Dechb,
                                              float* __restrict__ bc,
                                              float* __restrict__ te) {
    int t = blockIdx.x * 256 + threadIdx.x;
    if (t < 1024) {  // Enchb = fp16 frags of enc_w (128x64), K=128 -> 4 k-tiles
        int jt = t >> 8, kt = (t >> 6) & 3, l = t & 63;
        int j = jt * 16 + (l & 15);
        int kb = kt * 32 + (l >> 4) * 8;
#pragma unroll
        for (int i = 0; i < 8; ++i)
            Enchb[t * 8 + i] = (_Float16)enc_w[(kb + i) * 64 + j];
        return;
    }
    t -= 1024;
    if (t < 512) {  // Whb = fp16 frags of conv_w (64x64)
        int jt = t >> 7, kt = (t >> 6) & 1, l = t & 63;
        int j = jt * 16 + (l & 15);
        int kb = kt * 32 + (l >> 4) * 8;
#pragma unroll
        for (int i = 0; i < 8; ++i)
            Whb[t * 8 + i] = (_Float16)conv_w[(kb + i) * 64 + j];
        return;
    }
    t -= 512;
    if (t < 512) {  // W2hb = fp16 frags of conv_w @ res_w
        int jt = t >> 7, kt = (t >> 6) & 1, l = t & 63;
        int j = jt * 16 + (l & 15);
        int kb = kt * 32 + (l >> 4) * 8;
#pragma unroll
        for (int i = 0; i < 8; ++i) {
            int k = kb + i;
            float acc = 0.0f;
#pragma unroll 8
            for (int o = 0; o < 64; ++o)
                acc = fmaf(conv_w[k * 64 + o], res_w[o * 64 + j], acc);
            W2hb[t * 8 + i] = (_Float16)acc;
        }
        return;
    }
    t -= 512;
    if (t < 512) {  // Dechb = fp16 frags of dec_w (64x47, zero-padded)
        int jt = t >> 7, kt = (t >> 6) & 1, l = t & 63;
        int j = jt * 16 + (l & 15);
        int kb = kt * 32 + (l >> 4) * 8;
#pragma unroll
        for (int i = 0; i < 8; ++i) {
            int k = kb + i;
            Dechb[t * 8 + i] = (j < NCLASS) ? (_Float16)dec_w[k * NCLASS + j]
                                            : (_Float16)0.0f;
        }
        return;
    }
    t -= 512;
    if (t < NLAYERS * NHID) {
        te[t] = tanhf(eps[t]);
        if (t < NHID) bc[t] = conv_b[t] - res_b[t];
        if (t < NBUCK) gcur[t] = 0;
    }
}

// -------- phase 1: bucket edges by destination range (dense writes) ---------

__global__ __launch_bounds__(256) void k_bucket(const int* __restrict__ row,
                                                const int* __restrict__ col,
                                                int* __restrict__ gcur,
                                                unsigned int* __restrict__ buckets,
                                                int e) {
    __shared__ int lc[BK_EPB];
    __shared__ int lr[BK_EPB];
    __shared__ int cnt[NBUCK], basep[NBUCK], cnt2[NBUCK];
    const int tid = threadIdx.x;
    const int start = blockIdx.x * BK_EPB;
    const int m = min(BK_EPB, e - start);
    for (int i = tid; i < NBUCK; i += 256) { cnt[i] = 0; cnt2[i] = 0; }
    __syncthreads();
    for (int i = tid; i < m; i += 256) {
        int c = col[start + i];
        int r = row[start + i];
        lc[i] = c; lr[i] = r;
        atomicAdd(&cnt[c >> BSHIFT], 1);
    }
    __syncthreads();
    for (int i = tid; i < NBUCK; i += 256)
        if (cnt[i] > 0) basep[i] = atomicAdd(&gcur[i], cnt[i]);
    __syncthreads();
    for (int i = tid; i < m; i += 256) {
        int c = lc[i], r = lr[i];
        int s = c >> BSHIFT;
        int dst = basep[s] + atomicAdd(&cnt2[s], 1);
        if (dst < BCAP)
            buckets[(size_t)s * BCAP + dst] = ((unsigned)r << 16) | (unsigned)c;
    }
}

// -------- phase 2: one workgroup per bucket; cursors in LDS ----------------

__global__ __launch_bounds__(256) void k_fill2(const unsigned int* __restrict__ buckets,
                                               const int* __restrict__ gcur,
                                               int* __restrict__ deg,
                                               unsigned short* __restrict__ csr,
                                               int n) {
    __shared__ int cur[BSLICE];
    const int s = blockIdx.x;
    const int tid = threadIdx.x;
    for (int i = tid; i < BSLICE; i += 256) cur[i] = 0;
    __syncthreads();
    const int cnt = min(gcur[s], BCAP);
    const unsigned int* bp = buckets + (size_t)s * BCAP;
    for (int i = tid; i < cnt; i += 256) {
        unsigned int v = bp[i];
        int c = (int)(v & 0xffffu);
        int r = (int)(v >> 16);
        int pos = atomicAdd(&cur[c & (BSLICE - 1)], 1);
        if (pos < CAP) csr[(size_t)c * CAP + pos] = (unsigned short)r;
    }
    __syncthreads();
    const int base = s * BSLICE;
    const int nb = min(BSLICE, n - base);
    for (int i = tid; i < nb; i += 256) deg[base + i] = cur[i];
}

// -- dinv/rsq + sentinel-pad CSR rows + zero plane-layout sentinel rows ------

__global__ void k_dinv(const int* __restrict__ deg, float* __restrict__ dinv,
                       float* __restrict__ rsq, unsigned short* __restrict__ csr,
                       _Float16* __restrict__ Y0, _Float16* __restrict__ Y1, int n) {
    int i = blockIdx.x * blockDim.x + threadIdx.x;
    if (i < n) {
        int d = deg[i];
        if (d > CAP) d = CAP;
        float d1 = (float)(deg[i] + 1);
        dinv[i] = rsqrtf(d1);
        rsq[i] = sqrtf(d1);
        int end = (d + 7) & ~7;
        if (end > CAP) end = CAP;
        for (int s = d; s < end; ++s)
            csr[(size_t)i * CAP + s] = (unsigned short)n;  // sentinel -> zero row
    }
    if (i < 32) {   // zero sentinel rows (node n) in both planes of both buffers
        size_t PSh = (size_t)(n + 1) * 32;
        Y0[(size_t)n * 32 + i] = (_Float16)0.0f;
        Y0[PSh + (size_t)n * 32 + i] = (_Float16)0.0f;
        Y1[(size_t)n * 32 + i] = (_Float16)0.0f;
        Y1[PSh + (size_t)n * 32 + i] = (_Float16)0.0f;
    }
}

// ------- encoder via MFMA: Y0 = fp16( dinv * relu(x @ enc_w + enc_b) ) ------
// writes plane layout: Y[p][node][32], p = j>>5

__global__ __launch_bounds__(256) void k_encoder(const float* __restrict__ x,
                                                 const half8* __restrict__ Enchb,
                                                 const float* __restrict__ b,
                                                 const float* __restrict__ dinv,
                                                 _Float16* __restrict__ Y, int n) {
    __shared__ _Float16 Xe[16][XEW];
    const int wid = threadIdx.x >> 6;
    const int lane = threadIdx.x & 63;
    const int base = blockIdx.x * 16 + wid * 4;
    const size_t PSh = (size_t)(n + 1) * 32;

    {
        int nl = wid * 4 + ((threadIdx.x >> 4) & 3);
        int seg = threadIdx.x & 15;
        int node = blockIdx.x * 16 + nl;
        float4 u = make_float4(0.f, 0.f, 0.f, 0.f), v = u;
        if (node < n) {
            const float4* xp = reinterpret_cast<const float4*>(x + (size_t)node * NFEAT + seg * 8);
            u = xp[0]; v = xp[1];
        }
        half8 h;
        h[0] = (_Float16)u.x; h[1] = (_Float16)u.y; h[2] = (_Float16)u.z; h[3] = (_Float16)u.w;
        h[4] = (_Float16)v.x; h[5] = (_Float16)v.y; h[6] = (_Float16)v.z; h[7] = (_Float16)v.w;
        *reinterpret_cast<half8*>(&Xe[nl][seg * 8]) = h;
    }

    const int ar = (wid * 4 + (lane & 15)) & 15;
    const int aq = (lane >> 4) * 8;
    half8 a0 = *reinterpret_cast<const half8*>(&Xe[ar][0 * 32 + aq]);
    half8 a1 = *reinterpret_cast<const half8*>(&Xe[ar][1 * 32 + aq]);
    half8 a2 = *reinterpret_cast<const half8*>(&Xe[ar][2 * 32 + aq]);
    half8 a3 = *reinterpret_cast<const half8*>(&Xe[ar][3 * 32 + aq]);
    const f32x4 zero = {0.f, 0.f, 0.f, 0.f};

    float dvv[4];
#pragma unroll
    for (int i = 0; i < 4; ++i) dvv[i] = (base + i < n) ? dinv[base + i] : 0.f;

#pragma unroll
    for (int jt = 0; jt < 4; ++jt) {
        f32x4 dacc = __builtin_amdgcn_mfma_f32_16x16x32_f16(a0, Enchb[(jt * 4 + 0) * 64 + lane], zero, 0, 0, 0);
        dacc = __builtin_amdgcn_mfma_f32_16x16x32_f16(a1, Enchb[(jt * 4 + 1) * 64 + lane], dacc, 0, 0, 0);
        dacc = __builtin_amdgcn_mfma_f32_16x16x32_f16(a2, Enchb[(jt * 4 + 2) * 64 + lane], dacc, 0, 0, 0);
        dacc = __builtin_amdgcn_mfma_f32_16x16x32_f16(a3, Enchb[(jt * 4 + 3) * 64 + lane], dacc, 0, 0, 0);
        if (lane < 16) {
            int j = jt * 16 + lane;
            float bj = b[j];
#pragma unroll
            for (int i = 0; i < 4; ++i) {
                int node = base + i;
                if (node < n) {
                    float v = fmaxf(dacc[i] + bj, 0.0f);
                    Y[(size_t)(j >> 5) * PSh + (size_t)node * 32 + (j & 31)] =
                        (_Float16)(v * dvv[i]);
                }
            }
        }
    }
}

// ---------------- fused layer: plane-split gather + MFMA GEMMs + gate -------
// 16 nodes/block, 4 nodes/wave, ONE node per 16-lane group. No barriers.
// Y stored as 2 planes of (n+1)x32 fp16 (3.2 MB each -> per-XCD L2-resident
// per phase). Group lanes: c = l&3 (8-dim chunk), s = l>>2 (edge slot).
// Per instruction: 4 edges/group x 64B half-rows. Batch = 8 edges, 3-deep.

__global__ __launch_bounds__(256, 4) void k_layer(
    const half8* __restrict__ Y8c, _Float16* __restrict__ Ynext,
    const int* __restrict__ deg, const unsigned short* __restrict__ csr,
    const float* __restrict__ dinv, const float* __restrict__ rsq,
    const half8* __restrict__ Whb, const half8* __restrict__ W2hb,
    const half8* __restrict__ Dechb,
    const float* __restrict__ bc, const float* __restrict__ te,
    const float* __restrict__ dec_b, float* __restrict__ out, int n, int last) {
    __shared__ _Float16 Af[16][AFW];
    __shared__ _Float16 Xf[16][AFW];
    const int wid = threadIdx.x >> 6;
    const int lane = threadIdx.x & 63;
    const int g = lane >> 4;
    const int l = lane & 15;
    const int c = l & 3;                 // 8-dim chunk within the 32-dim half
    const int s = l >> 2;                // edge slot 0-3
    const unsigned sh2 = (unsigned)((s & 1) << 4);
    const int base = blockIdx.x * 16 + wid * 4;
    const int mynode = base + g;
    const bool gact = mynode < n;
    const int gn = gact ? mynode : 0;
    const int rown = gact ? mynode : n;
    const float dcg = dinv[gn];
    const float rcg = rsq[gn];
    int d = gact ? deg[gn] : 0;
    if (d > CAP) d = CAP;
    const int nit = (d + 7) >> 3;
    const size_t PS8 = (size_t)(n + 1) * 4;   // half8 units per plane
    const size_t PSh = (size_t)(n + 1) * 32;  // halves per plane

    const uint4* cpu4 = reinterpret_cast<const uint4*>(csr + (size_t)gn * CAP);

#pragma unroll
    for (int p = 0; p < 2; ++p) {
        const half8* Yp = Y8c + p * PS8;
        float acc[8] = {0.f, 0.f, 0.f, 0.f, 0.f, 0.f, 0.f, 0.f};

        // ---- 3-deep pipelined gather over this plane ----
        uint4 rA = cpu4[0];
        unsigned wa0 = (s >> 1) ? rA.y : rA.x;
        unsigned wa1 = (s >> 1) ? rA.w : rA.z;
        int ea0 = (int)((wa0 >> sh2) & 0xffffu);
        int ea1 = (int)((wa1 >> sh2) & 0xffffu);
        half8 A0 = Yp[(size_t)ea0 * 4 + c];
        half8 A1 = Yp[(size_t)ea1 * 4 + c];
        uint4 rB = cpu4[1];
        unsigned wb0 = (s >> 1) ? rB.y : rB.x;
        unsigned wb1 = (s >> 1) ? rB.w : rB.z;
        int eb0 = (int)((wb0 >> sh2) & 0xffffu);
        int eb1 = (int)((wb1 >> sh2) & 0xffffu);
        half8 B0 = Yp[(size_t)eb0 * 4 + c];
        half8 B1 = Yp[(size_t)eb1 * 4 + c];
        uint4 rC = cpu4[2];
        int it = 0;
        for (; it + 2 < nit; ++it) {
            unsigned wc0 = (s >> 1) ? rC.y : rC.x;
            unsigned wc1 = (s >> 1) ? rC.w : rC.z;
            int ec0 = (int)((wc0 >> sh2) & 0xffffu);
            int ec1 = (int)((wc1 >> sh2) & 0xffffu);
            half8 C0 = Yp[(size_t)ec0 * 4 + c];
            half8 C1 = Yp[(size_t)ec1 * 4 + c];
            rC = cpu4[it + 3];
#pragma unroll
            for (int i = 0; i < 8; ++i)
                acc[i] += (float)A0[i] + (float)A1[i];
            A0 = B0; A1 = B1;
            B0 = C0; B1 = C1;
        }
        if (it < nit) {
#pragma unroll
            for (int i = 0; i < 8; ++i)
                acc[i] += (float)A0[i] + (float)A1[i];
        }
        if (it + 1 < nit) {
#pragma unroll
            for (int i = 0; i < 8; ++i)
                acc[i] += (float)B0[i] + (float)B1[i];
        }
        // reduce over edge slots s (lane bits 2,3)
#pragma unroll
        for (int i = 0; i < 8; ++i) {
            acc[i] += __shfl_xor(acc[i], 4);
            acc[i] += __shfl_xor(acc[i], 8);
        }
        if (s == 0) {   // lanes 0-3 of group: finalize this plane's chunks
            half8 yc = Yp[(size_t)rown * 4 + c];
            half8 hg, hx;
#pragma unroll
            for (int i = 0; i < 8; ++i) {
                float ycf = (float)yc[i];
                hg[i] = (_Float16)((acc[i] + ycf) * dcg);
                hx[i] = (_Float16)(ycf * rcg);
            }
            *reinterpret_cast<half8*>(&Af[wid * 4 + g][p * 32 + c * 8]) = hg;
            *reinterpret_cast<half8*>(&Xf[wid * 4 + g][p * 32 + c * 8]) = hx;
        }
    }
    // (no barrier: this wave reads only rows wid*4..wid*4+3 as valid data)

    float dv[4];
#pragma unroll
    for (int i = 0; i < 4; ++i) dv[i] = __shfl(dcg, i * 16);

    // ---- MFMA GEMM phase ----
    const int ar = (wid * 4 + (lane & 15)) & 15;
    const int aq = (lane >> 4) * 8;
    half8 aG0 = *reinterpret_cast<const half8*>(&Af[ar][aq]);
    half8 aG1 = *reinterpret_cast<const half8*>(&Af[ar][32 + aq]);
    half8 aX0 = *reinterpret_cast<const half8*>(&Xf[ar][aq]);
    half8 aX1 = *reinterpret_cast<const half8*>(&Xf[ar][32 + aq]);
    const f32x4 zero = {0.f, 0.f, 0.f, 0.f};

#pragma unroll
    for (int jt = 0; jt < 4; ++jt) {
        half8 bG0 = Whb[(jt * 2 + 0) * 64 + lane];
        half8 bG1 = Whb[(jt * 2 + 1) * 64 + lane];
        half8 bX0 = W2hb[(jt * 2 + 0) * 64 + lane];
        half8 bX1 = W2hb[(jt * 2 + 1) * 64 + lane];
        f32x4 dG = __builtin_amdgcn_mfma_f32_16x16x32_f16(aG0, bG0, zero, 0, 0, 0);
        dG = __builtin_amdgcn_mfma_f32_16x16x32_f16(aG1, bG1, dG, 0, 0, 0);
        f32x4 dX = __builtin_amdgcn_mfma_f32_16x16x32_f16(aX0, bX0, zero, 0, 0, 0);
        dX = __builtin_amdgcn_mfma_f32_16x16x32_f16(aX1, bX1, dX, 0, 0, 0);
        if (lane < 16) {
            int j = jt * 16 + lane;
            float tej = te[j], bcj = bc[j];
#pragma unroll
            for (int i = 0; i < 4; ++i) {
                int node = base + i;
                float xf = (float)Xf[wid * 4 + i][j];
                float xn = xf * tej + fmaxf(dG[i] + bcj - dX[i], 0.0f);
                if (!last) {
                    if (node < n)
                        Ynext[(size_t)(j >> 5) * PSh + (size_t)node * 32 + (j & 31)] =
                            (_Float16)(xn * dv[i]);
                } else {
                    Af[wid * 4 + i][j] = (_Float16)xn;
                }
            }
        }
    }

    if (last) {  // decoder via MFMA (same-wave LDS ordering; no barrier)
        half8 aD0 = *reinterpret_cast<const half8*>(&Af[ar][aq]);
        half8 aD1 = *reinterpret_cast<const half8*>(&Af[ar][32 + aq]);
#pragma unroll
        for (int jt = 0; jt < 4; ++jt) {
            half8 bD0 = Dechb[(jt * 2 + 0) * 64 + lane];
            half8 bD1 = Dechb[(jt * 2 + 1) * 64 + lane];
            f32x4 dd = __builtin_amdgcn_mfma_f32_16x16x32_f16(aD0, bD0, zero, 0, 0, 0);
            dd = __builtin_amdgcn_mfma_f32_16x16x32_f16(aD1, bD1, dd, 0, 0, 0);
            if (lane < 16) {
                int j = jt * 16 + lane;
                if (j < NCLASS) {
                    float db = dec_b[j];
#pragma unroll
                    for (int i = 0; i < 4; ++i) {
                        int node = base + i;
                        if (node < n) out[(size_t)node * NCLASS + j] = dd[i] + db;
                    }
                }
            }
        }
    }
}

extern "C" void kernel_launch(void* const* d_in, const int* in_sizes, int n_in,
                              void* d_out, int out_size, void* d_ws, size_t ws_size,
                              hipStream_t stream) {
    const float* x      = (const float*)d_in[0];
    const int*   edges  = (const int*)d_in[1];
    const float* enc_w  = (const float*)d_in[2];
    const float* enc_b  = (const float*)d_in[3];
    const float* conv_w = (const float*)d_in[4];
    const float* conv_b = (const float*)d_in[5];
    const float* res_w  = (const float*)d_in[6];
    const float* res_b  = (const float*)d_in[7];
    const float* dec_w  = (const float*)d_in[8];
    const float* dec_b  = (const float*)d_in[9];
    const float* eps    = (const float*)d_in[10];
    float* out = (float*)d_out;

    const int n = in_sizes[0] / NFEAT;   // 50000
    const int e = in_sizes[1] / 2;       // 1250000
    const int* row = edges;
    const int* col = edges + e;

    // workspace layout (16B alignment maintained)
    char* p = (char*)d_ws;
    unsigned short* csr = (unsigned short*)p;
    p += ((size_t)n * CAP * 2 + 64 + 15) & ~(size_t)15;
    unsigned int* buckets = (unsigned int*)p;  p += (size_t)NBUCK * BCAP * 4;  // 8 MB
    _Float16* Y0 = (_Float16*)p;  p += (((size_t)(n + 1) * NHID * 2 + 127) & ~(size_t)127);
    _Float16* Y1 = (_Float16*)p;  p += (((size_t)(n + 1) * NHID * 2 + 127) & ~(size_t)127);
    int*   deg  = (int*)p;    p += (size_t)n * 4;
    float* dinv = (float*)p;  p += (size_t)n * 4;
    float* rsq  = (float*)p;  p += (size_t)n * 4;
    int*   gcur = (int*)p;    p += ((NBUCK + 15) & ~15) * 4;
    float* bc   = (float*)p;  p += NHID * 4;
    float* te   = (float*)p;  p += NLAYERS * NHID * 4;
    _Float16* Enchb = (_Float16*)p;  p += 8192 * 2;
    _Float16* Whb   = (_Float16*)p;  p += 4096 * 2;
    _Float16* W2hb  = (_Float16*)p;  p += 4096 * 2;
    _Float16* Dechb = (_Float16*)p;  p += 4096 * 2;
    if ((size_t)(p - (char*)d_ws) > ws_size) return;

    k_init<<<11, 256, 0, stream>>>(gcur, enc_w, conv_w, res_w, conv_b, res_b,
                                   eps, dec_w, Enchb, Whb, W2hb, Dechb, bc, te);
    const int bblocks = (e + BK_EPB - 1) / BK_EPB;
    k_bucket<<<bblocks, 256, 0, stream>>>(row, col, gcur, buckets, e);
    k_fill2<<<NBUCK, 256, 0, stream>>>(buckets, gcur, deg, csr, n);
    k_dinv<<<(n + 255) / 256, 256, 0, stream>>>(deg, dinv, rsq, csr, Y0, Y1, n);

    const int tblocks = (n + 15) / 16;
    k_encoder<<<tblocks, 256, 0, stream>>>(x, (const half8*)Enchb, enc_b, dinv, Y0, n);

    for (int l = 0; l < NLAYERS; ++l) {
        _Float16* ycur = (l & 1) ? Y1 : Y0;
        _Float16* ynxt = (l & 1) ? Y0 : Y1;
        k_layer<<<tblocks, 256, 0, stream>>>((const half8*)ycur, ynxt, deg, csr,
                                             dinv, rsq, (const half8*)Whb,
                                             (const half8*)W2hb, (const half8*)Dechb,
                                             bc, te + l * NHID, dec_b, out, n,
                                             (l == NLAYERS - 1) ? 1 : 0);
    }
}

// Round 16
// 220.062 us; speedup vs baseline: 1.0217x; 1.0217x over previous
//
#include <hip/hip_runtime.h>
#include <hip/hip_bf16.h>
#include <math.h>

#define NFEAT 128
#define NHID 64
#define NCLASS 47
#define NLAYERS 4
#define CAP 80       // max in-degree slots; deg ~ Poisson(25), P(>80) ~ 1e-17/node
#define NBUCK 128
#define BSHIFT 9     // bucket = c >> 9 (512 nodes per bucket)
#define BSLICE 512
#define BCAP 16384   // entries per bucket (mean 12.8K, +31 sigma headroom)
#define BK_EPB 2048
#define AFW 72       // fp16 LDS row stride (elements): 144 B
#define XEW 136      // encoder fp16 LDS row stride: 272 B

typedef __attribute__((ext_vector_type(8))) _Float16 half8;
typedef __attribute__((ext_vector_type(4))) float f32x4;

// -------- init: gcur + Y sentinels + fp16 MFMA B-frags (Enc,W,W2,Dec) + bc/te
// B-frag layout for mfma_f32_16x16x32_f16: lane l holds B[k][n], n = l&15,
// k = kt*32 + (l>>4)*8 + i (i=0..7). A uses the same slot->k bijection.

__global__ __launch_bounds__(256) void k_init(int* __restrict__ gcur,
                                              const float* __restrict__ enc_w,
                                              const float* __restrict__ conv_w,
                                              const float* __restrict__ res_w,
                                              const float* __restrict__ conv_b,
                                              const float* __restrict__ res_b,
                                              const float* __restrict__ eps,
                                              const float* __restrict__ dec_w,
                                              _Float16* __restrict__ Enchb,
                                              _Float16* __restrict__ Whb,
                                              _Float16* __restrict__ W2hb,
                                              _Float16* __restrict__ Dechb,
                                              float* __restrict__ bc,
                                              float* __restrict__ te,
                                              _Float16* __restrict__ Y0,
                                              _Float16* __restrict__ Y1,
                                              int n) {
    int t = blockIdx.x * 256 + threadIdx.x;
    if (t < 1024) {  // Enchb = fp16 frags of enc_w (128x64), K=128 -> 4 k-tiles
        int jt = t >> 8, kt = (t >> 6) & 3, l = t & 63;
        int j = jt * 16 + (l & 15);
        int kb = kt * 32 + (l >> 4) * 8;
#pragma unroll
        for (int i = 0; i < 8; ++i)
            Enchb[t * 8 + i] = (_Float16)enc_w[(kb + i) * 64 + j];
        return;
    }
    t -= 1024;
    if (t < 512) {  // Whb = fp16 frags of conv_w (64x64)
        int jt = t >> 7, kt = (t >> 6) & 1, l = t & 63;
        int j = jt * 16 + (l & 15);
        int kb = kt * 32 + (l >> 4) * 8;
#pragma unroll
        for (int i = 0; i < 8; ++i)
            Whb[t * 8 + i] = (_Float16)conv_w[(kb + i) * 64 + j];
        return;
    }
    t -= 512;
    if (t < 512) {  // W2hb = fp16 frags of conv_w @ res_w
        int jt = t >> 7, kt = (t >> 6) & 1, l = t & 63;
        int j = jt * 16 + (l & 15);
        int kb = kt * 32 + (l >> 4) * 8;
#pragma unroll
        for (int i = 0; i < 8; ++i) {
            int k = kb + i;
            float acc = 0.0f;
#pragma unroll 8
            for (int o = 0; o < 64; ++o)
                acc = fmaf(conv_w[k * 64 + o], res_w[o * 64 + j], acc);
            W2hb[t * 8 + i] = (_Float16)acc;
        }
        return;
    }
    t -= 512;
    if (t < 512) {  // Dechb = fp16 frags of dec_w (64x47, zero-padded)
        int jt = t >> 7, kt = (t >> 6) & 1, l = t & 63;
        int j = jt * 16 + (l & 15);
        int kb = kt * 32 + (l >> 4) * 8;
#pragma unroll
        for (int i = 0; i < 8; ++i) {
            int k = kb + i;
            Dechb[t * 8 + i] = (j < NCLASS) ? (_Float16)dec_w[k * NCLASS + j]
                                            : (_Float16)0.0f;
        }
        return;
    }
    t -= 512;
    if (t < NLAYERS * NHID) {
        te[t] = tanhf(eps[t]);
        if (t < NHID) bc[t] = conv_b[t] - res_b[t];
        if (t < NBUCK) gcur[t] = 0;
        if (t < 32) {  // zero sentinel rows (node n) in both planes of both bufs
            size_t PSh = (size_t)(n + 1) * 32;
            Y0[(size_t)n * 32 + t] = (_Float16)0.0f;
            Y0[PSh + (size_t)n * 32 + t] = (_Float16)0.0f;
            Y1[(size_t)n * 32 + t] = (_Float16)0.0f;
            Y1[PSh + (size_t)n * 32 + t] = (_Float16)0.0f;
        }
    }
}

// -------- phase 1: bucket edges by destination range (dense writes) ---------

__global__ __launch_bounds__(256) void k_bucket(const int* __restrict__ row,
                                                const int* __restrict__ col,
                                                int* __restrict__ gcur,
                                                unsigned int* __restrict__ buckets,
                                                int e) {
    __shared__ int lc[BK_EPB];
    __shared__ int lr[BK_EPB];
    __shared__ int cnt[NBUCK], basep[NBUCK], cnt2[NBUCK];
    const int tid = threadIdx.x;
    const int start = blockIdx.x * BK_EPB;
    const int m = min(BK_EPB, e - start);
    for (int i = tid; i < NBUCK; i += 256) { cnt[i] = 0; cnt2[i] = 0; }
    __syncthreads();
    for (int i = tid; i < m; i += 256) {
        int c = col[start + i];
        int r = row[start + i];
        lc[i] = c; lr[i] = r;
        atomicAdd(&cnt[c >> BSHIFT], 1);
    }
    __syncthreads();
    for (int i = tid; i < NBUCK; i += 256)
        if (cnt[i] > 0) basep[i] = atomicAdd(&gcur[i], cnt[i]);
    __syncthreads();
    for (int i = tid; i < m; i += 256) {
        int c = lc[i], r = lr[i];
        int s = c >> BSHIFT;
        int dst = basep[s] + atomicAdd(&cnt2[s], 1);
        if (dst < BCAP)
            buckets[(size_t)s * BCAP + dst] = ((unsigned)r << 16) | (unsigned)c;
    }
}

// -------- phase 2: one workgroup per bucket; cursors in LDS; also writes deg
// and sentinel-pads each CSR row to a multiple of 8 (fused former k_dinv) ----

__global__ __launch_bounds__(256) void k_fill2(const unsigned int* __restrict__ buckets,
                                               const int* __restrict__ gcur,
                                               int* __restrict__ deg,
                                               unsigned short* __restrict__ csr,
                                               int n) {
    __shared__ int cur[BSLICE];
    const int s = blockIdx.x;
    const int tid = threadIdx.x;
    for (int i = tid; i < BSLICE; i += 256) cur[i] = 0;
    __syncthreads();
    const int cnt = min(gcur[s], BCAP);
    const unsigned int* bp = buckets + (size_t)s * BCAP;
    for (int i = tid; i < cnt; i += 256) {
        unsigned int v = bp[i];
        int c = (int)(v & 0xffffu);
        int r = (int)(v >> 16);
        int pos = atomicAdd(&cur[c & (BSLICE - 1)], 1);
        if (pos < CAP) csr[(size_t)c * CAP + pos] = (unsigned short)r;
    }
    __syncthreads();
    const int base = s * BSLICE;
    const int nb = min(BSLICE, n - base);
    for (int i = tid; i < nb; i += 256) {
        int d0 = cur[i];
        deg[base + i] = d0;
        int d = min(d0, CAP);
        int end = (d + 7) & ~7;
        if (end > CAP) end = CAP;
        unsigned short* cp = csr + (size_t)(base + i) * CAP;
        for (int s2 = d; s2 < end; ++s2) cp[s2] = (unsigned short)n;
    }
}

// ------- encoder via MFMA: Y0 = fp16( dinv * relu(x @ enc_w + enc_b) ) ------
// dinv computed on the fly from deg; writes plane layout Y[p][node][32]

__global__ __launch_bounds__(256) void k_encoder(const float* __restrict__ x,
                                                 const half8* __restrict__ Enchb,
                                                 const float* __restrict__ b,
                                                 const int* __restrict__ deg,
                                                 _Float16* __restrict__ Y, int n) {
    __shared__ _Float16 Xe[16][XEW];
    const int wid = threadIdx.x >> 6;
    const int lane = threadIdx.x & 63;
    const int base = blockIdx.x * 16 + wid * 4;
    const size_t PSh = (size_t)(n + 1) * 32;

    {
        int nl = wid * 4 + ((threadIdx.x >> 4) & 3);
        int seg = threadIdx.x & 15;
        int node = blockIdx.x * 16 + nl;
        float4 u = make_float4(0.f, 0.f, 0.f, 0.f), v = u;
        if (node < n) {
            const float4* xp = reinterpret_cast<const float4*>(x + (size_t)node * NFEAT + seg * 8);
            u = xp[0]; v = xp[1];
        }
        half8 h;
        h[0] = (_Float16)u.x; h[1] = (_Float16)u.y; h[2] = (_Float16)u.z; h[3] = (_Float16)u.w;
        h[4] = (_Float16)v.x; h[5] = (_Float16)v.y; h[6] = (_Float16)v.z; h[7] = (_Float16)v.w;
        *reinterpret_cast<half8*>(&Xe[nl][seg * 8]) = h;
    }

    const int ar = (wid * 4 + (lane & 15)) & 15;
    const int aq = (lane >> 4) * 8;
    half8 a0 = *reinterpret_cast<const half8*>(&Xe[ar][0 * 32 + aq]);
    half8 a1 = *reinterpret_cast<const half8*>(&Xe[ar][1 * 32 + aq]);
    half8 a2 = *reinterpret_cast<const half8*>(&Xe[ar][2 * 32 + aq]);
    half8 a3 = *reinterpret_cast<const half8*>(&Xe[ar][3 * 32 + aq]);
    const f32x4 zero = {0.f, 0.f, 0.f, 0.f};

    float dvv[4];
#pragma unroll
    for (int i = 0; i < 4; ++i)
        dvv[i] = (base + i < n) ? rsqrtf((float)(deg[base + i] + 1)) : 0.f;

#pragma unroll
    for (int jt = 0; jt < 4; ++jt) {
        f32x4 dacc = __builtin_amdgcn_mfma_f32_16x16x32_f16(a0, Enchb[(jt * 4 + 0) * 64 + lane], zero, 0, 0, 0);
        dacc = __builtin_amdgcn_mfma_f32_16x16x32_f16(a1, Enchb[(jt * 4 + 1) * 64 + lane], dacc, 0, 0, 0);
        dacc = __builtin_amdgcn_mfma_f32_16x16x32_f16(a2, Enchb[(jt * 4 + 2) * 64 + lane], dacc, 0, 0, 0);
        dacc = __builtin_amdgcn_mfma_f32_16x16x32_f16(a3, Enchb[(jt * 4 + 3) * 64 + lane], dacc, 0, 0, 0);
        if (lane < 16) {
            int j = jt * 16 + lane;
            float bj = b[j];
#pragma unroll
            for (int i = 0; i < 4; ++i) {
                int node = base + i;
                if (node < n) {
                    float v = fmaxf(dacc[i] + bj, 0.0f);
                    Y[(size_t)(j >> 5) * PSh + (size_t)node * 32 + (j & 31)] =
                        (_Float16)(v * dvv[i]);
                }
            }
        }
    }
}

// ---------------- fused layer: plane-split gather + MFMA GEMMs + gate -------
// 16 nodes/block, 4 nodes/wave, ONE node per 16-lane group. No barriers.
// dinv/rsq computed on the fly from deg.

__global__ __launch_bounds__(256, 4) void k_layer(
    const half8* __restrict__ Y8c, _Float16* __restrict__ Ynext,
    const int* __restrict__ deg, const unsigned short* __restrict__ csr,
    const half8* __restrict__ Whb, const half8* __restrict__ W2hb,
    const half8* __restrict__ Dechb,
    const float* __restrict__ bc, const float* __restrict__ te,
    const float* __restrict__ dec_b, float* __restrict__ out, int n, int last) {
    __shared__ _Float16 Af[16][AFW];
    __shared__ _Float16 Xf[16][AFW];
    const int wid = threadIdx.x >> 6;
    const int lane = threadIdx.x & 63;
    const int g = lane >> 4;
    const int l = lane & 15;
    const int c = l & 3;                 // 8-dim chunk within the 32-dim half
    const int s = l >> 2;                // edge slot 0-3
    const unsigned sh2 = (unsigned)((s & 1) << 4);
    const int base = blockIdx.x * 16 + wid * 4;
    const int mynode = base + g;
    const bool gact = mynode < n;
    const int gn = gact ? mynode : 0;
    const int rown = gact ? mynode : n;
    int draw = gact ? deg[gn] : 0;
    float d1 = (float)(draw + 1);
    const float dcg = rsqrtf(d1);
    const float rcg = sqrtf(d1);
    int d = draw;
    if (d > CAP) d = CAP;
    const int nit = (d + 7) >> 3;
    const size_t PS8 = (size_t)(n + 1) * 4;   // half8 units per plane
    const size_t PSh = (size_t)(n + 1) * 32;  // halves per plane

    const uint4* cpu4 = reinterpret_cast<const uint4*>(csr + (size_t)gn * CAP);

#pragma unroll
    for (int p = 0; p < 2; ++p) {
        const half8* Yp = Y8c + p * PS8;
        float acc[8] = {0.f, 0.f, 0.f, 0.f, 0.f, 0.f, 0.f, 0.f};

        // ---- 3-deep pipelined gather over this plane ----
        uint4 rA = cpu4[0];
        unsigned wa0 = (s >> 1) ? rA.y : rA.x;
        unsigned wa1 = (s >> 1) ? rA.w : rA.z;
        int ea0 = (int)((wa0 >> sh2) & 0xffffu);
        int ea1 = (int)((wa1 >> sh2) & 0xffffu);
        half8 A0 = Yp[(size_t)ea0 * 4 + c];
        half8 A1 = Yp[(size_t)ea1 * 4 + c];
        uint4 rB = cpu4[1];
        unsigned wb0 = (s >> 1) ? rB.y : rB.x;
        unsigned wb1 = (s >> 1) ? rB.w : rB.z;
        int eb0 = (int)((wb0 >> sh2) & 0xffffu);
        int eb1 = (int)((wb1 >> sh2) & 0xffffu);
        half8 B0 = Yp[(size_t)eb0 * 4 + c];
        half8 B1 = Yp[(size_t)eb1 * 4 + c];
        uint4 rC = cpu4[2];
        int it = 0;
        for (; it + 2 < nit; ++it) {
            unsigned wc0 = (s >> 1) ? rC.y : rC.x;
            unsigned wc1 = (s >> 1) ? rC.w : rC.z;
            int ec0 = (int)((wc0 >> sh2) & 0xffffu);
            int ec1 = (int)((wc1 >> sh2) & 0xffffu);
            half8 C0 = Yp[(size_t)ec0 * 4 + c];
            half8 C1 = Yp[(size_t)ec1 * 4 + c];
            rC = cpu4[it + 3];
#pragma unroll
            for (int i = 0; i < 8; ++i)
                acc[i] += (float)A0[i] + (float)A1[i];
            A0 = B0; A1 = B1;
            B0 = C0; B1 = C1;
        }
        if (it < nit) {
#pragma unroll
            for (int i = 0; i < 8; ++i)
                acc[i] += (float)A0[i] + (float)A1[i];
        }
        if (it + 1 < nit) {
#pragma unroll
            for (int i = 0; i < 8; ++i)
                acc[i] += (float)B0[i] + (float)B1[i];
        }
        // reduce over edge slots s (lane bits 2,3)
#pragma unroll
        for (int i = 0; i < 8; ++i) {
            acc[i] += __shfl_xor(acc[i], 4);
            acc[i] += __shfl_xor(acc[i], 8);
        }
        if (s == 0) {   // lanes 0-3 of group: finalize this plane's chunks
            half8 yc = Yp[(size_t)rown * 4 + c];
            half8 hg, hx;
#pragma unroll
            for (int i = 0; i < 8; ++i) {
                float ycf = (float)yc[i];
                hg[i] = (_Float16)((acc[i] + ycf) * dcg);
                hx[i] = (_Float16)(ycf * rcg);
            }
            *reinterpret_cast<half8*>(&Af[wid * 4 + g][p * 32 + c * 8]) = hg;
            *reinterpret_cast<half8*>(&Xf[wid * 4 + g][p * 32 + c * 8]) = hx;
        }
    }
    // (no barrier: this wave reads only rows wid*4..wid*4+3 as valid data)

    float dv[4];
#pragma unroll
    for (int i = 0; i < 4; ++i) dv[i] = __shfl(dcg, i * 16);

    // ---- MFMA GEMM phase ----
    const int ar = (wid * 4 + (lane & 15)) & 15;
    const int aq = (lane >> 4) * 8;
    half8 aG0 = *reinterpret_cast<const half8*>(&Af[ar][aq]);
    half8 aG1 = *reinterpret_cast<const half8*>(&Af[ar][32 + aq]);
    half8 aX0 = *reinterpret_cast<const half8*>(&Xf[ar][aq]);
    half8 aX1 = *reinterpret_cast<const half8*>(&Xf[ar][32 + aq]);
    const f32x4 zero = {0.f, 0.f, 0.f, 0.f};

#pragma unroll
    for (int jt = 0; jt < 4; ++jt) {
        half8 bG0 = Whb[(jt * 2 + 0) * 64 + lane];
        half8 bG1 = Whb[(jt * 2 + 1) * 64 + lane];
        half8 bX0 = W2hb[(jt * 2 + 0) * 64 + lane];
        half8 bX1 = W2hb[(jt * 2 + 1) * 64 + lane];
        f32x4 dG = __builtin_amdgcn_mfma_f32_16x16x32_f16(aG0, bG0, zero, 0, 0, 0);
        dG = __builtin_amdgcn_mfma_f32_16x16x32_f16(aG1, bG1, dG, 0, 0, 0);
        f32x4 dX = __builtin_amdgcn_mfma_f32_16x16x32_f16(aX0, bX0, zero, 0, 0, 0);
        dX = __builtin_amdgcn_mfma_f32_16x16x32_f16(aX1, bX1, dX, 0, 0, 0);
        if (lane < 16) {
            int j = jt * 16 + lane;
            float tej = te[j], bcj = bc[j];
#pragma unroll
            for (int i = 0; i < 4; ++i) {
                int node = base + i;
                float xf = (float)Xf[wid * 4 + i][j];
                float xn = xf * tej + fmaxf(dG[i] + bcj - dX[i], 0.0f);
                if (!last) {
                    if (node < n)
                        Ynext[(size_t)(j >> 5) * PSh + (size_t)node * 32 + (j & 31)] =
                            (_Float16)(xn * dv[i]);
                } else {
                    Af[wid * 4 + i][j] = (_Float16)xn;
                }
            }
        }
    }

    if (last) {  // decoder via MFMA (same-wave LDS ordering; no barrier)
        half8 aD0 = *reinterpret_cast<const half8*>(&Af[ar][aq]);
        half8 aD1 = *reinterpret_cast<const half8*>(&Af[ar][32 + aq]);
#pragma unroll
        for (int jt = 0; jt < 4; ++jt) {
            half8 bD0 = Dechb[(jt * 2 + 0) * 64 + lane];
            half8 bD1 = Dechb[(jt * 2 + 1) * 64 + lane];
            f32x4 dd = __builtin_amdgcn_mfma_f32_16x16x32_f16(aD0, bD0, zero, 0, 0, 0);
            dd = __builtin_amdgcn_mfma_f32_16x16x32_f16(aD1, bD1, dd, 0, 0, 0);
            if (lane < 16) {
                int j = jt * 16 + lane;
                if (j < NCLASS) {
                    float db = dec_b[j];
#pragma unroll
                    for (int i = 0; i < 4; ++i) {
                        int node = base + i;
                        if (node < n) out[(size_t)node * NCLASS + j] = dd[i] + db;
                    }
                }
            }
        }
    }
}

extern "C" void kernel_launch(void* const* d_in, const int* in_sizes, int n_in,
                              void* d_out, int out_size, void* d_ws, size_t ws_size,
                              hipStream_t stream) {
    const float* x      = (const float*)d_in[0];
    const int*   edges  = (const int*)d_in[1];
    const float* enc_w  = (const float*)d_in[2];
    const float* enc_b  = (const float*)d_in[3];
    const float* conv_w = (const float*)d_in[4];
    const float* conv_b = (const float*)d_in[5];
    const float* res_w  = (const float*)d_in[6];
    const float* res_b  = (const float*)d_in[7];
    const float* dec_w  = (const float*)d_in[8];
    const float* dec_b  = (const float*)d_in[9];
    const float* eps    = (const float*)d_in[10];
    float* out = (float*)d_out;

    const int n = in_sizes[0] / NFEAT;   // 50000
    const int e = in_sizes[1] / 2;       // 1250000
    const int* row = edges;
    const int* col = edges + e;

    // workspace layout (16B alignment maintained)
    char* p = (char*)d_ws;
    unsigned short* csr = (unsigned short*)p;
    p += ((size_t)n * CAP * 2 + 64 + 15) & ~(size_t)15;
    unsigned int* buckets = (unsigned int*)p;  p += (size_t)NBUCK * BCAP * 4;  // 8 MB
    _Float16* Y0 = (_Float16*)p;  p += (((size_t)(n + 1) * NHID * 2 + 127) & ~(size_t)127);
    _Float16* Y1 = (_Float16*)p;  p += (((size_t)(n + 1) * NHID * 2 + 127) & ~(size_t)127);
    int*   deg  = (int*)p;    p += (size_t)n * 4;
    int*   gcur = (int*)p;    p += ((NBUCK + 15) & ~15) * 4;
    float* bc   = (float*)p;  p += NHID * 4;
    float* te   = (float*)p;  p += NLAYERS * NHID * 4;
    _Float16* Enchb = (_Float16*)p;  p += 8192 * 2;
    _Float16* Whb   = (_Float16*)p;  p += 4096 * 2;
    _Float16* W2hb  = (_Float16*)p;  p += 4096 * 2;
    _Float16* Dechb = (_Float16*)p;  p += 4096 * 2;
    if ((size_t)(p - (char*)d_ws) > ws_size) return;

    k_init<<<11, 256, 0, stream>>>(gcur, enc_w, conv_w, res_w, conv_b, res_b,
                                   eps, dec_w, Enchb, Whb, W2hb, Dechb, bc, te,
                                   Y0, Y1, n);
    const int bblocks = (e + BK_EPB - 1) / BK_EPB;
    k_bucket<<<bblocks, 256, 0, stream>>>(row, col, gcur, buckets, e);
    k_fill2<<<NBUCK, 256, 0, stream>>>(buckets, gcur, deg, csr, n);

    const int tblocks = (n + 15) / 16;
    k_encoder<<<tblocks, 256, 0, stream>>>(x, (const half8*)Enchb, enc_b, deg, Y0, n);

    for (int l = 0; l < NLAYERS; ++l) {
        _Float16* ycur = (l & 1) ? Y1 : Y0;
        _Float16* ynxt = (l & 1) ? Y0 : Y1;
        k_layer<<<tblocks, 256, 0, stream>>>((const half8*)ycur, ynxt, deg, csr,
                                             (const half8*)Whb,
                                             (const half8*)W2hb, (const half8*)Dechb,
                                             bc, te + l * NHID, dec_b, out, n,
                                             (l == NLAYERS - 1) ? 1 : 0);
    }
}